// Round 3
// baseline (555.361 us; speedup 1.0000x reference)
//
#include <hip/hip_runtime.h>

// Problem constants (from reference setup_inputs)
constexpr int B  = 32;
constexpr int H  = 224;
constexpr int W  = 224;
constexpr int C  = 64;
constexpr int OH = 112;   // ceil(224/2)
constexpr int OW = 112;
constexpr int C4 = C / 4; // 16 float4 groups per pixel

typedef float v4f __attribute__((ext_vector_type(4)));

__device__ __forceinline__ float gp_compute(float v00, float v01, float v10, float v11,
                                            float a, float u, float l,
                                            float lamb, bool topz, bool leftz)
{
    // zero-out padded taps (pad value is exactly 0.0, participates in max & sum)
    v01 = topz  ? 0.0f : v01;
    v10 = leftz ? 0.0f : v10;
    v00 = (topz || leftz) ? 0.0f : v00;
    float mx = fmaxf(fmaxf(v00, v01), fmaxf(v10, v11));
    float mn = (v00 + v01 + v10 + v11) * 0.25f;
    float d  = 2.0f * (fabsf(a - u) + fabsf(a - l));
    return (d > lamb) ? mx : mn;
}

__global__ __launch_bounds__(256)
void gradpool_kernel(const float* __restrict__ x,
                     const float* __restrict__ lamb_p,
                     float* __restrict__ out)
{
    const int idx = blockIdx.x * 256 + threadIdx.x;   // total 6,422,528 < 2^31

    const int c4 = idx & (C4 - 1);
    int t = idx >> 4;
    const int oj = t % OW; t /= OW;
    const int oi = t % OH;
    const int b  = t / OH;

    const float lamb = *lamb_p;

    // 32-bit element offsets throughout (max ~102.8M floats < 2^31)
    const float* xb = x + b * (H * W * C) + c4 * 4;

    auto ld = [&](int r, int w) -> v4f {
        return *(const v4f*)(xb + (r * W + w) * C);
    };

    const int r1 = 2 * oi;
    const int w1 = 2 * oj;
    const bool topz  = (oi == 0);
    const bool leftz = (oj == 0);
    const int rm = topz  ? 0 : r1 - 1;   // clamped (value zeroed in compute)
    const int wm = leftz ? 0 : w1 - 1;

    // 2x2 window (branch-free: clamped addresses, values zero-selected)
    v4f v11 = ld(r1, w1);
    v4f v01 = ld(rm, w1);
    v4f v10 = ld(r1, wm);
    v4f v00 = ld(rm, wm);

    // Selector taps (unstrided coords, always in [0,113))
    v4f a = ld(oi + 1, oj + 1);
    v4f u = ld(oi,     oj + 1);
    v4f l = ld(oi + 1, oj);

    v4f res;
    #pragma unroll
    for (int k = 0; k < 4; ++k) {
        res[k] = gp_compute(v00[k], v01[k], v10[k], v11[k],
                            a[k], u[k], l[k], lamb, topz, leftz);
    }

    float* op = out + ((b * OH + oi) * OW + oj) * C + c4 * 4;
    __builtin_nontemporal_store(res, (v4f*)op);
}

extern "C" void kernel_launch(void* const* d_in, const int* in_sizes, int n_in,
                              void* d_out, int out_size, void* d_ws, size_t ws_size,
                              hipStream_t stream)
{
    const float* x    = (const float*)d_in[0];
    const float* lamb = (const float*)d_in[1];
    float* out        = (float*)d_out;

    const int total = B * OH * OW * C4;               // 6,422,528
    const int block = 256;
    const int grid  = (total + block - 1) / block;    // 25,088

    gradpool_kernel<<<grid, block, 0, stream>>>(x, lamb, out);
}